// Round 1
// baseline (36.327 us; speedup 1.0000x reference)
//
#include <hip/hip_runtime.h>

// Output: [64, 2050, 14, 14] fp32.
// Channels [0,2048) = copy of img_feat; ch 2048 = x-map (j*2/14-1); ch 2049 = y-map (i*2/14-1).
// All work done as float4 (196 floats/channel = 49 float4s, all bases 16B-aligned).

#define B_IMG4 (2048 * 49)   // float4s of image part per batch = 100352
#define B_OUT4 (2050 * 49)   // float4s of output per batch     = 100450

__global__ __launch_bounds__(256) void AddSpatialInfo_kernel(
    const float4* __restrict__ in, float4* __restrict__ out, int total4) {
  for (int idx = blockIdx.x * blockDim.x + threadIdx.x; idx < total4;
       idx += gridDim.x * blockDim.x) {
    int b = idx / B_OUT4;
    int r = idx - b * B_OUT4;
    if (r < B_IMG4) {
      out[idx] = in[b * B_IMG4 + r];
    } else {
      int cr = r - B_IMG4;       // 0..97
      int ch = cr / 49;          // 0 -> x channel, 1 -> y channel
      int p4 = cr - ch * 49;     // float4 index within channel, 0..48
      float4 v;
      {
        int p = p4 * 4 + 0; int i = p / 14, j = p - i * 14;
        v.x = (ch == 0) ? (j * 2.0f / 14.0f - 1.0f) : (i * 2.0f / 14.0f - 1.0f);
      }
      {
        int p = p4 * 4 + 1; int i = p / 14, j = p - i * 14;
        v.y = (ch == 0) ? (j * 2.0f / 14.0f - 1.0f) : (i * 2.0f / 14.0f - 1.0f);
      }
      {
        int p = p4 * 4 + 2; int i = p / 14, j = p - i * 14;
        v.z = (ch == 0) ? (j * 2.0f / 14.0f - 1.0f) : (i * 2.0f / 14.0f - 1.0f);
      }
      {
        int p = p4 * 4 + 3; int i = p / 14, j = p - i * 14;
        v.w = (ch == 0) ? (j * 2.0f / 14.0f - 1.0f) : (i * 2.0f / 14.0f - 1.0f);
      }
      out[idx] = v;
    }
  }
}

extern "C" void kernel_launch(void* const* d_in, const int* in_sizes, int n_in,
                              void* d_out, int out_size, void* d_ws, size_t ws_size,
                              hipStream_t stream) {
  const float4* in = (const float4*)d_in[0];
  float4* out = (float4*)d_out;
  const int total4 = 64 * B_OUT4;  // 6,428,800 float4s
  const int block = 256;
  int blocks = (total4 + block - 1) / block;
  if (blocks > 2048) blocks = 2048;
  AddSpatialInfo_kernel<<<blocks, block, 0, stream>>>(in, out, total4);
}

// Round 3
// 36.042 us; speedup vs baseline: 1.0079x; 1.0079x over previous
//
#include <hip/hip_runtime.h>

// Output: [64, 2050, 14, 14] fp32.
// Channels [0,2048) = copy of img_feat; ch 2048 = x-map (j*2/14-1); ch 2049 = y-map (i*2/14-1).
// Per channel = 196 floats = 49 float4s. Per-batch: img = 2048*49 = 100352 float4s,
// out = 2050*49 = 100450 float4s. All bases 16B-aligned.
//
// Grid: (98, 64). blockIdx.y = batch, blockIdx.x = 1024-float4 chunk (256 thr x 4).
// Non-temporal stores (native clang vector type — HIP_vector_type not accepted
// by __builtin_nontemporal_store) keep the 103 MB input L3-resident.

typedef float f4 __attribute__((ext_vector_type(4)));

#define B_IMG4 100352  // 2048*49
#define B_OUT4 100450  // 2050*49

__global__ __launch_bounds__(256) void AddSpatialInfo_kernel(
    const f4* __restrict__ in, f4* __restrict__ out) {
  const int b = blockIdx.y;
  const int t = threadIdx.x;
  const int inBase  = b * B_IMG4 + blockIdx.x * 1024 + t;
  const int outBase = b * B_OUT4 + blockIdx.x * 1024 + t;
#pragma unroll
  for (int k = 0; k < 4; ++k) {
    f4 v = in[inBase + k * 256];
    __builtin_nontemporal_store(v, &out[outBase + k * 256]);
  }
  // Coord channels: 2 ch x 49 float4s = 98 float4s per batch, done by block x==0.
  if (blockIdx.x == 0 && t < 98) {
    const int ch = t / 49;        // 0 -> x channel, 1 -> y channel
    const int p4 = t - ch * 49;   // float4 index within channel
    f4 v;
#pragma unroll
    for (int m = 0; m < 4; ++m) {
      int p = p4 * 4 + m;         // 0..195
      int i = p / 14, j = p - i * 14;
      v[m] = (ch == 0) ? (j * 2.0f / 14.0f - 1.0f)
                       : (i * 2.0f / 14.0f - 1.0f);
    }
    __builtin_nontemporal_store(v, &out[b * B_OUT4 + B_IMG4 + t]);
  }
}

extern "C" void kernel_launch(void* const* d_in, const int* in_sizes, int n_in,
                              void* d_out, int out_size, void* d_ws, size_t ws_size,
                              hipStream_t stream) {
  const f4* in = (const f4*)d_in[0];
  f4* out = (f4*)d_out;
  dim3 grid(98, 64);  // 98 chunks of 1024 float4s cover 100352 float4s per batch
  AddSpatialInfo_kernel<<<grid, 256, 0, stream>>>(in, out);
}